// Round 15
// baseline (713.493 us; speedup 1.0000x reference)
//
#include <hip/hip_runtime.h>

#define NN 50000
#define NE 800000
#define NG 128
#define DIM 128
#define OUTD 64
#define NCONV 4
#define NB 196          // ceil(NN/256)
#define BN_EPS 1e-5f

typedef __attribute__((ext_vector_type(8))) short short8;
typedef __attribute__((ext_vector_type(4))) float f32x4;
union BF8 { uint4 u; short8 s; };

__device__ inline unsigned f2bf(float f) {   // RNE f32 -> bf16 bits
    unsigned u = __float_as_uint(f);
    return (u + 0x7FFFu + ((u >> 16) & 1u)) >> 16;
}
__device__ inline float bf_lo(unsigned u) { return __uint_as_float(u << 16); }
__device__ inline float bf_hi(unsigned u) { return __uint_as_float(u & 0xFFFF0000u); }

// ================= CSR build =================
__global__ __launch_bounds__(256) void k_degree(const int* __restrict__ dst,
                                                int* __restrict__ deg)
{
    int e = blockIdx.x * 256 + threadIdx.x;
    if (e < NE) atomicAdd(&deg[dst[e]], 1);
}

__global__ __launch_bounds__(256) void k_scan1(const int* __restrict__ deg,
                                               int* __restrict__ bsum)
{
    __shared__ int part[256];
    int t = threadIdx.x, idx = blockIdx.x * 256 + t;
    int v = (idx < NN) ? deg[idx] : 0;
    part[t] = v;
    __syncthreads();
    #pragma unroll
    for (int off = 1; off < 256; off <<= 1) {
        int u = (t >= off) ? part[t - off] : 0;
        __syncthreads();
        part[t] += u;
        __syncthreads();
    }
    if (t == 255) bsum[blockIdx.x] = part[255];
}

__global__ __launch_bounds__(256) void k_scan2(const int* __restrict__ bsum,
                                               int* __restrict__ boff)
{
    __shared__ int part[256];
    int t = threadIdx.x;
    int v = (t < NB) ? bsum[t] : 0;
    part[t] = v;
    __syncthreads();
    #pragma unroll
    for (int off = 1; off < 256; off <<= 1) {
        int u = (t >= off) ? part[t - off] : 0;
        __syncthreads();
        part[t] += u;
        __syncthreads();
    }
    if (t < NB) boff[t] = part[t] - v;   // exclusive
}

__global__ __launch_bounds__(256) void k_scan3(const int* __restrict__ deg,
                                               const int* __restrict__ boff,
                                               int* __restrict__ rowptr,
                                               int* __restrict__ cursor)
{
    __shared__ int part[256];
    int t = threadIdx.x, idx = blockIdx.x * 256 + t;
    int v = (idx < NN) ? deg[idx] : 0;
    part[t] = v;
    __syncthreads();
    #pragma unroll
    for (int off = 1; off < 256; off <<= 1) {
        int u = (t >= off) ? part[t - off] : 0;
        __syncthreads();
        part[t] += u;
        __syncthreads();
    }
    if (idx < NN) {
        int excl = part[t] - v + boff[blockIdx.x];
        rowptr[idx] = excl;
        cursor[idx] = excl;
    }
    if (idx == 0) rowptr[NN] = NE;
}

__global__ __launch_bounds__(256) void k_fill(const int* __restrict__ src,
                                              const int* __restrict__ dst,
                                              int* __restrict__ cursor,
                                              int* __restrict__ csr)
{
    int e = blockIdx.x * 256 + threadIdx.x;
    if (e >= NE) return;
    int pos = atomicAdd(&cursor[dst[e]], 1);
    csr[pos] = src[e];
}

__global__ __launch_bounds__(256) void k_bounds(const int* __restrict__ gid,
                                                int* __restrict__ gstart)
{
    int n = blockIdx.x * 256 + threadIdx.x;
    if (n >= NN) return;
    int g = gid[n];
    int gp = (n == 0) ? -1 : gid[n - 1];
    for (int x = gp + 1; x <= g; ++x) gstart[x] = n;
    if (n == NN - 1)
        for (int x = g + 1; x <= NG; ++x) gstart[x] = NN;
}

// ====== W -> bf16, MFMA-B fragment order: [mat][kk][ctg][lane][8] ======
__global__ __launch_bounds__(256) void k_wprep(const float* __restrict__ W1,
                                               const float* __restrict__ W2,
                                               unsigned short* __restrict__ Wbf)
{
    int tid = blockIdx.x * 256 + threadIdx.x;   // 16384
    int l   = tid & 63;
    int ctg = (tid >> 6) & 7;
    int kk  = (tid >> 9) & 3;
    int mat = tid >> 11;
    const float* Ws = (mat < 4) ? (W1 + (size_t)mat * DIM * DIM)
                                : (W2 + (size_t)(mat - 4) * DIM * DIM);
    int col = ctg * 16 + (l & 15);
    int k0  = kk * 32 + (l >> 4) * 8;
    unsigned sh[8];
    #pragma unroll
    for (int j = 0; j < 8; ++j) sh[j] = f2bf(Ws[(size_t)(k0 + j) * DIM + col]);
    uint4 pk;
    pk.x = sh[0] | (sh[1] << 16); pk.y = sh[2] | (sh[3] << 16);
    pk.z = sh[4] | (sh[5] << 16); pk.w = sh[6] | (sh[7] << 16);
    ((uint4*)Wbf)[tid] = pk;
}

// ====== fp32 -> bf16 bulk convert (layer-0 h) ======
__global__ __launch_bounds__(256) void k_cvt(const float* __restrict__ in,
                                             unsigned short* __restrict__ outb)
{
    int idx = blockIdx.x * 256 + threadIdx.x;   // per 4 elements
    if (idx >= NN * DIM / 4) return;
    float4 v = ((const float4*)in)[idx];
    uint2 pk;
    pk.x = f2bf(v.x) | (f2bf(v.y) << 16);
    pk.y = f2bf(v.z) | (f2bf(v.w) << 16);
    ((uint2*)outb)[idx] = pk;
}

// --- per-thread BN affine for 4 channels ch0..ch0+3 ---
__device__ inline void bn_affine4(const float* __restrict__ sumP,
                                  const float* __restrict__ sqP,
                                  const float* __restrict__ gP,
                                  const float* __restrict__ bP,
                                  int ch0, float4& av, float4& cv)
{
    const float invM = 1.f / (float)NN;
    #pragma unroll
    for (int j = 0; j < 4; ++j) {
        int ch = ch0 + j;
        float m = sumP[ch] * invM;
        float var = sqP[ch] * invM - m * m;
        float s = gP[ch] * rsqrtf(var + BN_EPS);
        (&av.x)[j] = s;
        (&cv.x)[j] = bP[ch] - m * s;
    }
}

__device__ inline float4 aff_relu(float4 v, const float4 av, const float4 cv)
{
    v.x = fmaxf(fmaf(v.x, av.x, cv.x), 0.f);
    v.y = fmaxf(fmaf(v.y, av.y, cv.y), 0.f);
    v.z = fmaxf(fmaf(v.z, av.z, cv.z), 0.f);
    v.w = fmaxf(fmaf(v.w, av.w, cv.w), 0.f);
    return v;
}

// ===== segmented pooling: reads bf16 z (or fp32 h), BN affine, pool + hbf =====
template<bool AFFINE, bool WRITEH, bool INBF16>
__global__ __launch_bounds__(256) void k_poolseg(
    const void* __restrict__ z_,
    const float* __restrict__ sumP, const float* __restrict__ sqP,
    const float* __restrict__ gP, const float* __restrict__ bP,
    const int* __restrict__ gstart, float* __restrict__ pooled,
    unsigned short* __restrict__ hbf)
{
    const int g = blockIdx.x >> 2, split = blockIdx.x & 3;
    const int s = gstart[g], e = gstart[g + 1];
    const int len = e - s;
    const int chunk = (len + 3) >> 2;
    const int rs = s + split * chunk;
    const int re = min(e, rs + chunk);
    const int c4 = threadIdx.x & 31, rl = threadIdx.x >> 5;
    float4 av, cv;
    if (AFFINE) bn_affine4(sumP, sqP, gP, bP, c4 * 4, av, cv);
    float4 acc = make_float4(0.f, 0.f, 0.f, 0.f);
    for (int r = rs + rl; r < re; r += 8) {
        float4 v;
        if (INBF16) {
            uint2 w = ((const uint2*)z_)[(size_t)r * 32 + c4];
            v = make_float4(bf_lo(w.x), bf_hi(w.x), bf_lo(w.y), bf_hi(w.y));
        } else {
            v = ((const float4*)z_)[(size_t)r * 32 + c4];
        }
        if (AFFINE) v = aff_relu(v, av, cv);
        if (WRITEH) {
            uint2 pk;
            pk.x = f2bf(v.x) | (f2bf(v.y) << 16);
            pk.y = f2bf(v.z) | (f2bf(v.w) << 16);
            ((uint2*)(hbf + (size_t)r * DIM))[c4] = pk;
        }
        acc.x += v.x; acc.y += v.y; acc.z += v.z; acc.w += v.w;
    }
    __shared__ float4 red[8][32];
    red[rl][c4] = acc;
    __syncthreads();
    if (rl == 0) {
        float4 s4 = red[0][c4];
        #pragma unroll
        for (int r8 = 1; r8 < 8; ++r8) {
            float4 u = red[r8][c4];
            s4.x += u.x; s4.y += u.y; s4.z += u.z; s4.w += u.w;
        }
        float* p = pooled + (size_t)g * DIM + c4 * 4;
        atomicAdd(p + 0, s4.x);
        atomicAdd(p + 1, s4.y);
        atomicAdd(p + 2, s4.z);
        atomicAdd(p + 3, s4.w);
    }
}

// ============ MFMA bf16 GEMM, bf16 in/out, fused gather or affine ============
// GATHER=true : X = hbf; wave-per-row neighbor-sum (4 neighbors in flight/wave,
//               lanes j=lane>>4 x q=lane&15, shfl_xor reduce), fp32 accum.
// GATHER=false, AFFINE=true: X = z1 bf16; BN1 affine+relu on stage-in.
// 64-row tile, 256 threads (4 waves). wave w: rows (w>>1)*32..+31, cols (w&1)*64..+63.
// Output Z bf16 + fp32 column stats (from fp32 accumulators — exact).
template<bool GATHER, bool AFFINE>
__global__ __launch_bounds__(256) void k_gemm_mfma(
    const unsigned short* __restrict__ Xb,
    const int* __restrict__ rowptr, const int* __restrict__ csr,
    const float* __restrict__ sumP, const float* __restrict__ sqP,
    const float* __restrict__ gP, const float* __restrict__ bP,
    const unsigned short* __restrict__ Wbf,     // fragment layout, one matrix
    unsigned short* __restrict__ Z,             // bf16 out
    float* __restrict__ colsum, float* __restrict__ colsq)
{
    __shared__ unsigned short a_lds[16 * 520];   // 16.6 KB (padded groups)
    const int t = threadIdx.x;
    const int row0 = blockIdx.x * 64;
    const uint4* hp4 = (const uint4*)Xb;         // row stride 16 uint4

    if (GATHER) {
        // ---- wave-per-row gather: j = neighbor slot (4), q = 16B chunk (16) ----
        const int wv = t >> 6, lane = t & 63;
        const int j = lane >> 4, q = lane & 15;
        for (int rr = 0; rr < 16; ++rr) {
            int row = wv * 16 + rr;
            int grow = row0 + row;
            bool valid = grow < NN;
            float a[8] = {0.f, 0.f, 0.f, 0.f, 0.f, 0.f, 0.f, 0.f};
            if (valid) {
                if (j == 0) {                    // self term, counted once
                    uint4 v = hp4[(size_t)grow * 16 + q];
                    a[0] = bf_lo(v.x); a[1] = bf_hi(v.x);
                    a[2] = bf_lo(v.y); a[3] = bf_hi(v.y);
                    a[4] = bf_lo(v.z); a[5] = bf_hi(v.z);
                    a[6] = bf_lo(v.w); a[7] = bf_hi(v.w);
                }
                int p = rowptr[grow], end = rowptr[grow + 1];
                for (; p + 4 <= end; p += 4) {
                    int s = csr[p + j];
                    uint4 u = hp4[(size_t)s * 16 + q];
                    a[0] += bf_lo(u.x); a[1] += bf_hi(u.x);
                    a[2] += bf_lo(u.y); a[3] += bf_hi(u.y);
                    a[4] += bf_lo(u.z); a[5] += bf_hi(u.z);
                    a[6] += bf_lo(u.w); a[7] += bf_hi(u.w);
                }
                if (p + j < end) {
                    int s = csr[p + j];
                    uint4 u = hp4[(size_t)s * 16 + q];
                    a[0] += bf_lo(u.x); a[1] += bf_hi(u.x);
                    a[2] += bf_lo(u.y); a[3] += bf_hi(u.y);
                    a[4] += bf_lo(u.z); a[5] += bf_hi(u.z);
                    a[6] += bf_lo(u.w); a[7] += bf_hi(u.w);
                }
            }
            #pragma unroll
            for (int i = 0; i < 8; ++i) {        // fold 4 neighbor groups
                a[i] += __shfl_xor(a[i], 16);
                a[i] += __shfl_xor(a[i], 32);
            }
            if (j == 0) {
                uint4 pk = make_uint4(0, 0, 0, 0);
                if (valid) {
                    pk.x = f2bf(a[0]) | (f2bf(a[1]) << 16);
                    pk.y = f2bf(a[2]) | (f2bf(a[3]) << 16);
                    pk.z = f2bf(a[4]) | (f2bf(a[5]) << 16);
                    pk.w = f2bf(a[6]) | (f2bf(a[7]) << 16);
                }
                int g = (row >> 4) * 4 + (q >> 2);
                int l = (row & 15) + (q & 3) * 16;
                *(uint4*)(a_lds + g * 520 + l * 8) = pk;
            }
        }
    } else {
        // ---- 16-threads-per-row stage: bf16 load (+ optional BN1 affine) ----
        const int q = t & 15;
        float av[8], cv[8];
        if (AFFINE) {
            const float invM = 1.f / (float)NN;
            #pragma unroll
            for (int jj = 0; jj < 8; ++jj) {
                int ch = q * 8 + jj;
                float m = sumP[ch] * invM;
                float var = sqP[ch] * invM - m * m;
                float sc = gP[ch] * rsqrtf(var + BN_EPS);
                av[jj] = sc; cv[jj] = bP[ch] - m * sc;
            }
        }
        #pragma unroll
        for (int it = 0; it < 4; ++it) {
            int row = (t >> 4) + it * 16;        // 0..63
            int grow = row0 + row;
            uint4 pk = make_uint4(0, 0, 0, 0);
            if (grow < NN) {
                uint4 v = hp4[(size_t)grow * 16 + q];
                if (AFFINE) {
                    float a[8];
                    a[0] = bf_lo(v.x); a[1] = bf_hi(v.x);
                    a[2] = bf_lo(v.y); a[3] = bf_hi(v.y);
                    a[4] = bf_lo(v.z); a[5] = bf_hi(v.z);
                    a[6] = bf_lo(v.w); a[7] = bf_hi(v.w);
                    #pragma unroll
                    for (int jj = 0; jj < 8; ++jj)
                        a[jj] = fmaxf(fmaf(a[jj], av[jj], cv[jj]), 0.f);
                    pk.x = f2bf(a[0]) | (f2bf(a[1]) << 16);
                    pk.y = f2bf(a[2]) | (f2bf(a[3]) << 16);
                    pk.z = f2bf(a[4]) | (f2bf(a[5]) << 16);
                    pk.w = f2bf(a[6]) | (f2bf(a[7]) << 16);
                } else {
                    pk = v;
                }
            }
            int g = (row >> 4) * 4 + (q >> 2);
            int l = (row & 15) + (q & 3) * 16;
            *(uint4*)(a_lds + g * 520 + l * 8) = pk;
        }
    }
    __syncthreads();

    const int w = t >> 6, lane = t & 63;
    const int rh = w >> 1, ch = w & 1;
    f32x4 acc[2][4];
    #pragma unroll
    for (int i = 0; i < 2; ++i)
        #pragma unroll
        for (int j = 0; j < 4; ++j) acc[i][j] = 0;

    const uint4* Wb = (const uint4*)Wbf;
    #pragma unroll
    for (int kk = 0; kk < 4; ++kk) {
        BF8 a[2], b[4];
        #pragma unroll
        for (int rti = 0; rti < 2; ++rti) {
            int g = (rh * 2 + rti) * 4 + kk;
            a[rti].u = *(const uint4*)(a_lds + g * 520 + lane * 8);
        }
        #pragma unroll
        for (int ct = 0; ct < 4; ++ct)
            b[ct].u = Wb[(kk * 8 + ch * 4 + ct) * 64 + lane];
        #pragma unroll
        for (int rti = 0; rti < 2; ++rti)
            #pragma unroll
            for (int ct = 0; ct < 4; ++ct)
                acc[rti][ct] = __builtin_amdgcn_mfma_f32_16x16x32_bf16(
                    a[rti].s, b[ct].s, acc[rti][ct], 0, 0, 0);
    }

    // ---- epilogue: store Z (bf16) + column stats from fp32 acc ----
    float ps[4] = {0.f, 0.f, 0.f, 0.f}, pq[4] = {0.f, 0.f, 0.f, 0.f};
    #pragma unroll
    for (int rti = 0; rti < 2; ++rti) {
        #pragma unroll
        for (int r = 0; r < 4; ++r) {
            int grow = row0 + rh * 32 + rti * 16 + (lane >> 4) * 4 + r;
            if (grow < NN) {
                #pragma unroll
                for (int ct = 0; ct < 4; ++ct) {
                    float v = acc[rti][ct][r];
                    Z[(size_t)grow * DIM + ch * 64 + ct * 16 + (lane & 15)] =
                        (unsigned short)f2bf(v);
                    ps[ct] += v;
                    pq[ct] += v * v;
                }
            }
        }
    }
    __syncthreads();                 // all LDS A-reads done
    float* red = (float*)a_lds;      // [256]: 0..127 sum, 128..255 sq
    red[t] = 0.f;
    __syncthreads();
    #pragma unroll
    for (int ct = 0; ct < 4; ++ct) {
        int col = ch * 64 + ct * 16 + (lane & 15);
        atomicAdd(&red[col], ps[ct]);
        atomicAdd(&red[128 + col], pq[ct]);
    }
    __syncthreads();
    if (t < DIM) {
        atomicAdd(colsum + t, red[t]);
        atomicAdd(colsq + t, red[128 + t]);
    }
}

// ======= final: out[g][o] = sum_i pooled_i[g] @ predW_i[:,o] + predb_i[o] =======
// One block per graph, 5 waves (one per rep), LDS reduce, single plain store.
__global__ __launch_bounds__(320) void k_score(const float* __restrict__ pooled,
                                               const float* __restrict__ predW,
                                               const float* __restrict__ predb,
                                               float* __restrict__ out)
{
    __shared__ float red[5][OUTD];
    const int g = blockIdx.x;
    const int w = threadIdx.x >> 6;      // rep 0..4
    const int o = threadIdx.x & 63;
    const float* pr = pooled + (size_t)w * NG * DIM + (size_t)g * DIM;
    const float* Wp = predW + (size_t)w * DIM * OUTD;
    float acc = predb[w * OUTD + o];
    #pragma unroll 8
    for (int k = 0; k < DIM; ++k) acc = fmaf(pr[k], Wp[k * OUTD + o], acc);
    red[w][o] = acc;
    __syncthreads();
    if (threadIdx.x < OUTD) {
        float s = red[0][o] + red[1][o] + red[2][o] + red[3][o] + red[4][o];
        out[(size_t)g * OUTD + o] = s;
    }
}

extern "C" void kernel_launch(void* const* d_in, const int* in_sizes, int n_in,
                              void* d_out, int out_size, void* d_ws, size_t ws_size,
                              hipStream_t stream)
{
    const float* h     = (const float*)d_in[0];
    const int*   esrc  = (const int*)d_in[1];
    const int*   edst  = (const int*)d_in[2];
    const int*   gid   = (const int*)d_in[3];
    const float* W1    = (const float*)d_in[4];
    const float* bn1g  = (const float*)d_in[5];
    const float* bn1b  = (const float*)d_in[6];
    const float* W2    = (const float*)d_in[7];
    const float* bn2g  = (const float*)d_in[8];
    const float* bn2b  = (const float*)d_in[9];
    const float* predW = (const float*)d_in[10];
    const float* predb = (const float*)d_in[11];
    float* out = (float*)d_out;

    float* ws = (float*)d_ws;
    const size_t NF = (size_t)NN * DIM;        // 6.4M elements
    float* pooled = ws;                        // 5*128*128
    float* stats  = pooled + 5 * NG * DIM;     // 4 layers * 1024
    // per layer: [0]=sum1 [128]=sq1 [512]=sum2 [640]=sq2

    unsigned short* hbf  = (unsigned short*)(stats + NCONV * 1024);  // NF bf16
    unsigned short* z1b  = hbf + NF;                                  // NF bf16
    unsigned short* z2b  = z1b + NF;                                  // NF bf16
    unsigned short* Wbf  = z2b + NF;                                  // 8*16384 bf16
    int* ideg   = (int*)(Wbf + 8 * 16384);
    int* rowptr = ideg + NN;                   // NN+1
    int* cursor = rowptr + NN + 1;
    int* csr    = cursor + NN;                 // NE
    int* gstart = csr + NE;                    // NG+1
    int* bsum   = gstart + NG + 1;             // NB
    int* boff   = bsum + NB;                   // NB

    hipMemsetAsync(pooled, 0, (5 * NG * DIM + NCONV * 1024) * sizeof(float), stream);
    hipMemsetAsync(ideg, 0, NN * sizeof(int), stream);

    // W -> bf16 fragments, h -> bf16, CSR, graph bounds
    k_wprep<<<64, 256, 0, stream>>>(W1, W2, Wbf);
    k_cvt<<<(NN * DIM / 4 + 255) / 256, 256, 0, stream>>>(h, hbf);
    k_degree<<<(NE + 255) / 256, 256, 0, stream>>>(edst, ideg);
    k_scan1<<<NB, 256, 0, stream>>>(ideg, bsum);
    k_scan2<<<1, 256, 0, stream>>>(bsum, boff);
    k_scan3<<<NB, 256, 0, stream>>>(ideg, boff, rowptr, cursor);
    k_fill<<<(NE + 255) / 256, 256, 0, stream>>>(esrc, edst, cursor, csr);
    k_bounds<<<(NN + 255) / 256, 256, 0, stream>>>(gid, gstart);

    // pooled[0] from fp32 h (exact), no affine, no h-write
    k_poolseg<false, false, false><<<NG * 4, 256, 0, stream>>>(
        h, nullptr, nullptr, nullptr, nullptr, gstart, pooled, nullptr);

    const int GB = (NN + 63) / 64;   // 782
    for (int i = 0; i < NCONV; ++i) {
        float* st = stats + i * 1024;
        // GEMM1: gather-fused (agg = hbf + neighbor sum), out z1 bf16 + stats1
        k_gemm_mfma<true, false><<<GB, 256, 0, stream>>>(
            hbf, rowptr, csr, nullptr, nullptr, nullptr, nullptr,
            Wbf + (size_t)i * 16384, z1b, st, st + 128);
        // GEMM2: BN1 affine+relu on stage-in, out z2 bf16 + stats2
        k_gemm_mfma<false, true><<<GB, 256, 0, stream>>>(
            z1b, nullptr, nullptr, st, st + 128, bn1g + i * DIM, bn1b + i * DIM,
            Wbf + (size_t)(4 + i) * 16384, z2b, st + 512, st + 640);
        // pool (+ write next-layer hbf except last layer)
        if (i < NCONV - 1)
            k_poolseg<true, true, true><<<NG * 4, 256, 0, stream>>>(
                z2b, st + 512, st + 640, bn2g + i * DIM, bn2b + i * DIM,
                gstart, pooled + (size_t)(i + 1) * NG * DIM, hbf);
        else
            k_poolseg<true, false, true><<<NG * 4, 256, 0, stream>>>(
                z2b, st + 512, st + 640, bn2g + i * DIM, bn2b + i * DIM,
                gstart, pooled + (size_t)(i + 1) * NG * DIM, nullptr);
    }

    k_score<<<NG, 320, 0, stream>>>(pooled, predW, predb, out);
}